// Round 9
// baseline (129.272 us; speedup 1.0000x reference)
//
#include <hip/hip_runtime.h>
#include <hip/hip_bf16.h>

#define B_ 8
#define T_ 2048
#define C_ 768
#define H_ 64
#define BT_ (B_*T_)

typedef __attribute__((ext_vector_type(8))) short bf16x8;
typedef __attribute__((ext_vector_type(4))) float f32x4;

__device__ __forceinline__ unsigned short f2bf(float x) {
    __hip_bfloat16 h = __float2bfloat16(x);   // RNE
    return __builtin_bit_cast(unsigned short, h);
}

__device__ __forceinline__ bf16x8 cvt8(float4 a, float4 b) {
    bf16x8 r;
    r[0] = (short)f2bf(a.x); r[1] = (short)f2bf(a.y);
    r[2] = (short)f2bf(a.z); r[3] = (short)f2bf(a.w);
    r[4] = (short)f2bf(b.x); r[5] = (short)f2bf(b.y);
    r[6] = (short)f2bf(b.z); r[7] = (short)f2bf(b.w);
    return r;
}

// ------------- W prep (coalesced): block = (m, gc); LDS transpose ---------------
__global__ __launch_bounds__(256) void wprep(
    const float* __restrict__ Wq, const float* __restrict__ Wk,
    const float* __restrict__ Wv, unsigned short* __restrict__ WTf)
{
    __shared__ float tile[32][68];
    const int bid = blockIdx.x;              // 72 = 3 m * 24 gc
    const int m = bid / 24, gc = bid % 24;
    const float* __restrict__ W = (m == 0) ? Wq : (m == 1) ? Wk : Wv;
    const int t = threadIdx.x;
    {
        const int r = t >> 3, c0 = (t & 7) * 8;
        float4 a = *(const float4*)(W + (size_t)(gc * 32 + r) * H_ + c0);
        float4 b = *(const float4*)(W + (size_t)(gc * 32 + r) * H_ + c0 + 4);
        *(float4*)&tile[r][c0]     = a;
        *(float4*)&tile[r][c0 + 4] = b;
    }
    __syncthreads();
    const int fl = t >> 6, lane = t & 63;
    const int q16 = lane & 15, quad = lane >> 4;
    const int f = m * 4 + fl;
    ushort4 u0, u1;
    u0.x = f2bf(tile[quad * 8 + 0][fl * 16 + q16]);
    u0.y = f2bf(tile[quad * 8 + 1][fl * 16 + q16]);
    u0.z = f2bf(tile[quad * 8 + 2][fl * 16 + q16]);
    u0.w = f2bf(tile[quad * 8 + 3][fl * 16 + q16]);
    u1.x = f2bf(tile[quad * 8 + 4][fl * 16 + q16]);
    u1.y = f2bf(tile[quad * 8 + 5][fl * 16 + q16]);
    u1.z = f2bf(tile[quad * 8 + 6][fl * 16 + q16]);
    u1.w = f2bf(tile[quad * 8 + 7][fl * 16 + q16]);
    unsigned short* __restrict__ dst = WTf + ((size_t)(gc * 12 + f) * 64 + lane) * 8;
    *(ushort4*)(dst)     = u0;
    *(ushort4*)(dst + 4) = u1;
}

// ------------- QKV via MFMA: barrier-free, direct-from-global x -----------------
// R24. Ledger: qkv = 23.8us measured (R21 delta) vs ~12us overlap model; traffic
// cuts lose (R19), TLP-up loses (R23), staged-pipeline null (R22 — defeated by
// in-order vmem retirement: staging loads issued before W loads force W
// consumers to drain them). Surviving theory: the stage->barrier->compute
// structure itself serializes the HBM and L2 phases chip-wide (1024 co-resident
// blocks in lockstep). Fix: ELIMINATE the phases. The MFMA x-fragment
// x[rowBase+q16][c*32+quad*8..+8) is a contiguous 32B f32 load in exactly the
// needed layout (per instruction: 16 tokens x 128B contiguous — coalesced), so
// load x directly from global per chunk, cvt in-register, MFMA. No LDS, no
// barrier, uniform load stream the compiler can pipeline freely. Costs 4x x
// reads (waves don't share) but 3/4 hit L1/L2 (4 waves sweep the same 48KB in
// lockstep); in-loop cvt ~= removed staging VALU. unroll 6 + (256,6) bounds
// in-flight regs <= 85 (R21 spill lesson).
__global__ __launch_bounds__(256, 6) void qkv_kernel(
    const float* __restrict__ x, const unsigned short* __restrict__ WTf,
    unsigned short* __restrict__ qF, unsigned short* __restrict__ kF,
    unsigned short* __restrict__ vF)
{
    const int tid  = threadIdx.x;
    const int w    = tid >> 6;               // f-set 0..3
    const int lane = tid & 63;
    const int q16  = lane & 15, quad = lane >> 4;
    const int rowBase = blockIdx.x << 4;

    const int f0 = w * 3;
    const float* __restrict__ xrow = x + (size_t)(rowBase + q16) * C_ + quad * 8;
    f32x4 acc[3] = {};
    #pragma unroll 6
    for (int c = 0; c < 24; c++) {
        const unsigned short* __restrict__ wpc =
            WTf + ((size_t)(c * 12 + f0)) * 512 + lane * 8;
        float4 a = *(const float4*)(xrow + c * 32);
        float4 b = *(const float4*)(xrow + c * 32 + 4);
        bf16x8 xf = cvt8(a, b);
        bf16x8 w0 = *(const bf16x8*)(wpc);
        bf16x8 w1 = *(const bf16x8*)(wpc + 512);
        bf16x8 w2 = *(const bf16x8*)(wpc + 1024);
        acc[0] = __builtin_amdgcn_mfma_f32_16x16x32_bf16(w0, xf, acc[0], 0, 0, 0);
        acc[1] = __builtin_amdgcn_mfma_f32_16x16x32_bf16(w1, xf, acc[1], 0, 0, 0);
        acc[2] = __builtin_amdgcn_mfma_f32_16x16x32_bf16(w2, xf, acc[2], 0, 0, 0);
    }

    // ---- fragment-packed epilogue (R11 mapping), run by ALL waves in parallel
    const size_t gt = (size_t)(rowBase >> 4);
    #pragma unroll
    for (int j = 0; j < 3; j++) {
        const int f = f0 + j;                // wave-uniform
        if (f < 8) {
            ushort4 u;
            u.x = f2bf(acc[j][0]); u.y = f2bf(acc[j][1]);
            u.z = f2bf(acc[j][2]); u.w = f2bf(acc[j][3]);
            const int n4 = f & 3;
            const int qp = (2 * n4 + (quad >> 1)) & 3;
            const int j0 = (quad & 1) * 4;
            unsigned short* __restrict__ dst = (f < 4) ? qF : kF;
            *(ushort4*)(dst + ((gt * 2 + (n4 >> 1)) * 64 + q16 + 16 * qp) * 8 + j0) = u;
        } else {
            const size_t g32 = gt >> 1;
            const int qv = ((int)gt & 1) * 2 + (q16 >> 3);
            const int jv = q16 & 7;
            #pragma unroll
            for (int r = 0; r < 4; r++)
                vF[((g32 * 4 + (f - 8)) * 64 + quad * 4 + r + 16 * qv) * 8 + jv] =
                    f2bf(acc[j][r]);
        }
    }
}

// ------------- MFMA flash attention: 4-wave k-split, 2 q-tiles/block ------------
// R20 config (measured best: 114.55 us; untouched — isolate the qkv variable).
__global__ __launch_bounds__(256) void attn_kernel(
    const unsigned short* __restrict__ qF, const unsigned short* __restrict__ kF,
    const unsigned short* __restrict__ vF, const float* __restrict__ mask,
    float* __restrict__ out)
{
    __shared__ __align__(16) unsigned short pS[4][16][88];  // wave-private P tiles
    __shared__ float oS[3][64][17];          // o[16] + l in slot 16; stride 17 odd

    const int tid  = threadIdx.x;
    const int w    = tid >> 6;
    const int lane = tid & 63;
    const int q16  = lane & 15;
    const int quad = lane >> 4;
    const int bid  = blockIdx.x;
    const int b    = bid & 7;                    // batches interleaved (XCD affinity)
    const int g    = 63 - (bid >> 3);            // heavy q-pairs first (LPT)
    const int qtA  = 2 * g, qtB = 2 * g + 1;
    const int qrowA = (qtA << 4) + q16;
    const int qrowB = qrowA + 16;

    const size_t qbaseA = ((size_t)(b * 128 + qtA) * 2) * 512 + lane * 8;
    const size_t qbaseB = ((size_t)(b * 128 + qtB) * 2) * 512 + lane * 8;
    bf16x8 qfA0 = *(const bf16x8*)(qF + qbaseA);
    bf16x8 qfA1 = *(const bf16x8*)(qF + qbaseA + 512);
    bf16x8 qfB0 = *(const bf16x8*)(qF + qbaseB);
    bf16x8 qfB1 = *(const bf16x8*)(qF + qbaseB + 512);
    // fold 1/sqrt(64) and log2(e): softmax runs in base-2 domain
    const float mrowA  = mask[b * T_ + qrowA];
    const float mrowB  = mask[b * T_ + qrowB];
    const float maskvA = mrowA * 0.125f * 1.44269504f;
    const float maskvB = mrowB * 0.125f * 1.44269504f;

    f32x4 oA[4] = {}, oB[4] = {};
    float lA = 0.f, lB = 0.f;

    const int niter = ((qtB << 4) + 16 + 63) >> 6;  // same for qtA
    const int dt    = niter - 1;                    // diagonal tile index

    bf16x8 kf[8], vf[8];
    auto loadK = [&](int kt_) {
        #pragma unroll
        for (int sub = 0; sub < 4; sub++) {
            const unsigned short* kp = kF + ((size_t)(b * 128 + kt_ * 4 + sub) * 2) * 512 + lane * 8;
            kf[2 * sub]     = *(const bf16x8*)(kp);
            kf[2 * sub + 1] = *(const bf16x8*)(kp + 512);
        }
    };
    auto loadV = [&](int kt_) {
        #pragma unroll
        for (int ht = 0; ht < 4; ht++) {
            const unsigned short* vp = vF + ((size_t)(b * 64 + kt_ * 2) * 4 + ht) * 512 + lane * 8;
            vf[2 * ht]     = *(const bf16x8*)(vp);
            vf[2 * ht + 1] = *(const bf16x8*)(vp + 4 * 512);
        }
    };

    if (w < niter) { loadK(w); loadV(w); }       // prologue (wave-uniform guard)

    for (int kt = w; kt < niter; kt += 4) {
        const int kbase = kt << 6;
        const bool more = (kt + 4 < niter);      // wave-uniform

        // ---- S^T = K.Q^T for BOTH tiles (kf dies after saB)
        f32x4 saA[4] = {}, saB[4] = {};
        #pragma unroll
        for (int sub = 0; sub < 4; sub++) {
            saA[sub] = __builtin_amdgcn_mfma_f32_16x16x32_bf16(kf[2 * sub],     qfA0, saA[sub], 0, 0, 0);
            saA[sub] = __builtin_amdgcn_mfma_f32_16x16x32_bf16(kf[2 * sub + 1], qfA1, saA[sub], 0, 0, 0);
            saB[sub] = __builtin_amdgcn_mfma_f32_16x16x32_bf16(kf[2 * sub],     qfB0, saB[sub], 0, 0, 0);
            saB[sub] = __builtin_amdgcn_mfma_f32_16x16x32_bf16(kf[2 * sub + 1], qfB1, saB[sub], 0, 0, 0);
        }
        if (more) loadK(kt + 4);                 // prefetch next K into dead kf

        // ---- tile A: softmax + PV  (pS[w] used then released)
        {
            float p[16];
            if (kt != dt) {
                #pragma unroll
                for (int e = 0; e < 16; e++)
                    p[e] = __builtin_amdgcn_exp2f(saA[e >> 2][e & 3] * maskvA);
            } else {
                #pragma unroll
                for (int sub = 0; sub < 4; sub++)
                    #pragma unroll
                    for (int r = 0; r < 4; r++) {
                        int kidx = kbase + sub * 16 + quad * 4 + r;
                        float sv = saA[sub][r] * maskvA;
                        sv = (kidx > qrowA) ? -__builtin_inff() : sv;
                        p[sub * 4 + r] = __builtin_amdgcn_exp2f(sv);
                    }
            }
            lA += (((p[0] + p[1]) + (p[2] + p[3])) + ((p[4] + p[5]) + (p[6] + p[7])))
                + (((p[8] + p[9]) + (p[10] + p[11])) + ((p[12] + p[13]) + (p[14] + p[15])));
            #pragma unroll
            for (int sub = 0; sub < 4; sub++) {
                unsigned int lo = (unsigned int)f2bf(p[sub * 4 + 0]) | ((unsigned int)f2bf(p[sub * 4 + 1]) << 16);
                unsigned int hi = (unsigned int)f2bf(p[sub * 4 + 2]) | ((unsigned int)f2bf(p[sub * 4 + 3]) << 16);
                *(uint2*)&pS[w][q16][sub * 16 + quad * 4] = make_uint2(lo, hi);
            }
            bf16x8 pf0 = *(const bf16x8*)&pS[w][q16][quad * 8];
            bf16x8 pf1 = *(const bf16x8*)&pS[w][q16][32 + quad * 8];
            #pragma unroll
            for (int ht = 0; ht < 4; ht++) {
                oA[ht] = __builtin_amdgcn_mfma_f32_16x16x32_bf16(vf[2 * ht],     pf0, oA[ht], 0, 0, 0);
                oA[ht] = __builtin_amdgcn_mfma_f32_16x16x32_bf16(vf[2 * ht + 1], pf1, oA[ht], 0, 0, 0);
            }
        }

        // ---- tile B: softmax + PV  (pS[w] reused; intra-wave WAR ordering)
        {
            float p[16];
            if (kt != dt) {
                #pragma unroll
                for (int e = 0; e < 16; e++)
                    p[e] = __builtin_amdgcn_exp2f(saB[e >> 2][e & 3] * maskvB);
            } else {
                #pragma unroll
                for (int sub = 0; sub < 4; sub++)
                    #pragma unroll
                    for (int r = 0; r < 4; r++) {
                        int kidx = kbase + sub * 16 + quad * 4 + r;
                        float sv = saB[sub][r] * maskvB;
                        sv = (kidx > qrowB) ? -__builtin_inff() : sv;
                        p[sub * 4 + r] = __builtin_amdgcn_exp2f(sv);
                    }
            }
            lB += (((p[0] + p[1]) + (p[2] + p[3])) + ((p[4] + p[5]) + (p[6] + p[7])))
                + (((p[8] + p[9]) + (p[10] + p[11])) + ((p[12] + p[13]) + (p[14] + p[15])));
            #pragma unroll
            for (int sub = 0; sub < 4; sub++) {
                unsigned int lo = (unsigned int)f2bf(p[sub * 4 + 0]) | ((unsigned int)f2bf(p[sub * 4 + 1]) << 16);
                unsigned int hi = (unsigned int)f2bf(p[sub * 4 + 2]) | ((unsigned int)f2bf(p[sub * 4 + 3]) << 16);
                *(uint2*)&pS[w][q16][sub * 16 + quad * 4] = make_uint2(lo, hi);
            }
            bf16x8 pf0 = *(const bf16x8*)&pS[w][q16][quad * 8];
            bf16x8 pf1 = *(const bf16x8*)&pS[w][q16][32 + quad * 8];
            #pragma unroll
            for (int ht = 0; ht < 4; ht++) {
                oB[ht] = __builtin_amdgcn_mfma_f32_16x16x32_bf16(vf[2 * ht],     pf0, oB[ht], 0, 0, 0);
                oB[ht] = __builtin_amdgcn_mfma_f32_16x16x32_bf16(vf[2 * ht + 1], pf1, oB[ht], 0, 0, 0);
            }
        }
        if (more) loadV(kt + 4);                 // prefetch next V into dead vf
    }

    // deferred cross-lane l reduction (k spans the quad dimension)
    lA += __shfl_xor(lA, 16); lA += __shfl_xor(lA, 32);
    lB += __shfl_xor(lB, 16); lB += __shfl_xor(lB, 32);

    // ---- merge tile A (oS reused for B afterwards)
    if (w > 0) {
        #pragma unroll
        for (int ht = 0; ht < 4; ht++)
            #pragma unroll
            for (int r = 0; r < 4; r++) oS[w - 1][lane][ht * 4 + r] = oA[ht][r];
        oS[w - 1][lane][16] = lA;
    }
    __syncthreads();
    if (w == 0) {
        #pragma unroll
        for (int j = 0; j < 3; j++) {
            #pragma unroll
            for (int ht = 0; ht < 4; ht++)
                #pragma unroll
                for (int r = 0; r < 4; r++) oA[ht][r] += oS[j][lane][ht * 4 + r];
            lA += oS[j][lane][16];
        }
        const float invl = (mrowA != 0.f && lA > 0.f) ? (1.f / lA) : 0.f;
        #pragma unroll
        for (int ht = 0; ht < 4; ht++) {
            float4 ov = make_float4(oA[ht][0] * invl, oA[ht][1] * invl,
                                    oA[ht][2] * invl, oA[ht][3] * invl);
            *(float4*)(out + ((size_t)(b * T_) + qrowA) * H_ + ht * 16 + quad * 4) = ov;
        }
    }
    __syncthreads();                             // w0 done reading oS(A)

    // ---- merge tile B
    if (w > 0) {
        #pragma unroll
        for (int ht = 0; ht < 4; ht++)
            #pragma unroll
            for (int r = 0; r < 4; r++) oS[w - 1][lane][ht * 4 + r] = oB[ht][r];
        oS[w - 1][lane][16] = lB;
    }
    __syncthreads();
    if (w == 0) {
        #pragma unroll
        for (int j = 0; j < 3; j++) {
            #pragma unroll
            for (int ht = 0; ht < 4; ht++)
                #pragma unroll
                for (int r = 0; r < 4; r++) oB[ht][r] += oS[j][lane][ht * 4 + r];
            lB += oS[j][lane][16];
        }
        const float invl = (mrowB != 0.f && lB > 0.f) ? (1.f / lB) : 0.f;
        #pragma unroll
        for (int ht = 0; ht < 4; ht++) {
            float4 ov = make_float4(oB[ht][0] * invl, oB[ht][1] * invl,
                                    oB[ht][2] * invl, oB[ht][3] * invl);
            *(float4*)(out + ((size_t)(b * T_) + qrowB) * H_ + ht * 16 + quad * 4) = ov;
        }
    }
}

extern "C" void kernel_launch(void* const* d_in, const int* in_sizes, int n_in,
                              void* d_out, int out_size, void* d_ws, size_t ws_size,
                              hipStream_t stream) {
    const float* x    = (const float*)d_in[0];
    const float* mask = (const float*)d_in[1];
    const float* Wq   = (const float*)d_in[2];
    const float* Wk   = (const float*)d_in[3];
    const float* Wv   = (const float*)d_in[4];
    float* out = (float*)d_out;

    unsigned short* qf = (unsigned short*)d_ws;            // bf16 frag-packed [BT*H]
    unsigned short* kf = qf + (size_t)BT_ * H_;
    unsigned short* vf = kf + (size_t)BT_ * H_;
    unsigned short* wt = vf + (size_t)BT_ * H_;            // bf16 WTf[24][12][64][8]

    wprep<<<72, 256, 0, stream>>>(Wq, Wk, Wv, wt);
    qkv_kernel<<<BT_ / 16, 256, 0, stream>>>(x, wt, qf, kf, vf);
    attn_kernel<<<B_ * (T_ / 32), 256, 0, stream>>>(qf, kf, vf, mask, out);
}

// Round 10
// 112.633 us; speedup vs baseline: 1.1477x; 1.1477x over previous
//
#include <hip/hip_runtime.h>
#include <hip/hip_bf16.h>

#define B_ 8
#define T_ 2048
#define C_ 768
#define H_ 64
#define BT_ (B_*T_)

typedef __attribute__((ext_vector_type(8))) short bf16x8;
typedef __attribute__((ext_vector_type(4))) float f32x4;

__device__ __forceinline__ unsigned short f2bf(float x) {
    __hip_bfloat16 h = __float2bfloat16(x);   // RNE
    return __builtin_bit_cast(unsigned short, h);
}

__device__ __forceinline__ bf16x8 cvt8(float4 a, float4 b) {
    bf16x8 r;
    r[0] = (short)f2bf(a.x); r[1] = (short)f2bf(a.y);
    r[2] = (short)f2bf(a.z); r[3] = (short)f2bf(a.w);
    r[4] = (short)f2bf(b.x); r[5] = (short)f2bf(b.y);
    r[6] = (short)f2bf(b.z); r[7] = (short)f2bf(b.w);
    return r;
}

// ------------- W prep (coalesced): block = (m, gc); LDS transpose ---------------
__global__ __launch_bounds__(256) void wprep(
    const float* __restrict__ Wq, const float* __restrict__ Wk,
    const float* __restrict__ Wv, unsigned short* __restrict__ WTf)
{
    __shared__ float tile[32][68];
    const int bid = blockIdx.x;              // 72 = 3 m * 24 gc
    const int m = bid / 24, gc = bid % 24;
    const float* __restrict__ W = (m == 0) ? Wq : (m == 1) ? Wk : Wv;
    const int t = threadIdx.x;
    {
        const int r = t >> 3, c0 = (t & 7) * 8;
        float4 a = *(const float4*)(W + (size_t)(gc * 32 + r) * H_ + c0);
        float4 b = *(const float4*)(W + (size_t)(gc * 32 + r) * H_ + c0 + 4);
        *(float4*)&tile[r][c0]     = a;
        *(float4*)&tile[r][c0 + 4] = b;
    }
    __syncthreads();
    const int fl = t >> 6, lane = t & 63;
    const int q16 = lane & 15, quad = lane >> 4;
    const int f = m * 4 + fl;
    ushort4 u0, u1;
    u0.x = f2bf(tile[quad * 8 + 0][fl * 16 + q16]);
    u0.y = f2bf(tile[quad * 8 + 1][fl * 16 + q16]);
    u0.z = f2bf(tile[quad * 8 + 2][fl * 16 + q16]);
    u0.w = f2bf(tile[quad * 8 + 3][fl * 16 + q16]);
    u1.x = f2bf(tile[quad * 8 + 4][fl * 16 + q16]);
    u1.y = f2bf(tile[quad * 8 + 5][fl * 16 + q16]);
    u1.z = f2bf(tile[quad * 8 + 6][fl * 16 + q16]);
    u1.w = f2bf(tile[quad * 8 + 7][fl * 16 + q16]);
    unsigned short* __restrict__ dst = WTf + ((size_t)(gc * 12 + f) * 64 + lane) * 8;
    *(ushort4*)(dst)     = u0;
    *(ushort4*)(dst + 4) = u1;
}

// ------------- QKV via MFMA: R14 structure + depth-4 W prefetch pipeline --------
// R25. Diagnosis from R21/R24 counters: qkv is dependence-chain LATENCY-bound
// (MfmaUtil ~4%, VALUBusy ~5%, everything idle). R14's loop exposes ~160cy of
// L2 latency per c-iter (only ~1 iter of load lookahead scheduled). TLP can't
// fix it (R23 worse; grid caps residency at 4 blocks/CU). Fix the PIPELINE
// DEPTH instead, at zero occupancy cost:
//  (1) __launch_bounds__(256,4): 4 waves/SIMD is all the grid can deliver
//      anyway (1024 blocks / 256 CU = 4 blocks/CU); raises VGPR cap 85 -> 128.
//  (2) explicit depth-4 rolling W prefetch (wbuf[4][3] = 48 VGPR, indices
//      compile-time under full unroll): every MFMA's W operands were issued 4
//      iters (~120-160cy) earlier; compiler emits counted vmcnt leaving newer
//      loads in flight. Staging, LDS layout, traffic, epilogue: unchanged.
__global__ __launch_bounds__(256, 4) void qkv_kernel(
    const float* __restrict__ x, const unsigned short* __restrict__ WTf,
    unsigned short* __restrict__ qF, unsigned short* __restrict__ kF,
    unsigned short* __restrict__ vF)
{
    __shared__ __align__(16) unsigned short xS[16 * 772];   // 24.7 KB, padded rows
    const int tid  = threadIdx.x;
    const int w    = tid >> 6;               // f-set 0..3
    const int lane = tid & 63;
    const int q16  = lane & 15, quad = lane >> 4;
    const int rowBase = blockIdx.x << 4;

    // ---- stage x: thread t = (row t>>4, l=t&15); 6 x 32B contiguous per thread
    {
        const int r = tid >> 4, l = tid & 15;
        const float* __restrict__ xrow = x + (size_t)(rowBase + r) * C_;
        #pragma unroll
        for (int i = 0; i < 6; i++) {
            const int j = i * 16 + l;        // 32B granule 0..95
            float4 a = *(const float4*)(xrow + j * 8);
            float4 b = *(const float4*)(xrow + j * 8 + 4);
            *(bf16x8*)&xS[(size_t)r * 772 + j * 8] = cvt8(a, b);
        }
    }
    __syncthreads();                          // the only barrier

    const int f0 = w * 3;
    const unsigned short* __restrict__ xrowS = xS + q16 * 772 + quad * 8;
    const unsigned short* __restrict__ wbase = WTf + (size_t)f0 * 512 + lane * 8;

    // depth-4 rolling prefetch of W (wbuf index is compile-time under unroll)
    bf16x8 wbuf[4][3];
    #pragma unroll
    for (int i = 0; i < 4; i++) {
        const unsigned short* __restrict__ wp = wbase + (size_t)i * 12 * 512;
        wbuf[i][0] = *(const bf16x8*)(wp);
        wbuf[i][1] = *(const bf16x8*)(wp + 512);
        wbuf[i][2] = *(const bf16x8*)(wp + 1024);
    }

    f32x4 acc[3] = {};
    #pragma unroll
    for (int c = 0; c < 24; c++) {
        bf16x8 xf = *(const bf16x8*)(xrowS + c * 32);   // ds_read_b128, <=2-way
        acc[0] = __builtin_amdgcn_mfma_f32_16x16x32_bf16(wbuf[c & 3][0], xf, acc[0], 0, 0, 0);
        acc[1] = __builtin_amdgcn_mfma_f32_16x16x32_bf16(wbuf[c & 3][1], xf, acc[1], 0, 0, 0);
        acc[2] = __builtin_amdgcn_mfma_f32_16x16x32_bf16(wbuf[c & 3][2], xf, acc[2], 0, 0, 0);
        if (c + 4 < 24) {
            const unsigned short* __restrict__ wp = wbase + (size_t)(c + 4) * 12 * 512;
            wbuf[c & 3][0] = *(const bf16x8*)(wp);
            wbuf[c & 3][1] = *(const bf16x8*)(wp + 512);
            wbuf[c & 3][2] = *(const bf16x8*)(wp + 1024);
        }
    }

    // ---- fragment-packed epilogue (R11 mapping), run by ALL waves in parallel
    const size_t gt = (size_t)(rowBase >> 4);
    #pragma unroll
    for (int j = 0; j < 3; j++) {
        const int f = f0 + j;                // wave-uniform
        if (f < 8) {
            ushort4 u;
            u.x = f2bf(acc[j][0]); u.y = f2bf(acc[j][1]);
            u.z = f2bf(acc[j][2]); u.w = f2bf(acc[j][3]);
            const int n4 = f & 3;
            const int qp = (2 * n4 + (quad >> 1)) & 3;
            const int j0 = (quad & 1) * 4;
            unsigned short* __restrict__ dst = (f < 4) ? qF : kF;
            *(ushort4*)(dst + ((gt * 2 + (n4 >> 1)) * 64 + q16 + 16 * qp) * 8 + j0) = u;
        } else {
            const size_t g32 = gt >> 1;
            const int qv = ((int)gt & 1) * 2 + (q16 >> 3);
            const int jv = q16 & 7;
            #pragma unroll
            for (int r = 0; r < 4; r++)
                vF[((g32 * 4 + (f - 8)) * 64 + quad * 4 + r + 16 * qv) * 8 + jv] =
                    f2bf(acc[j][r]);
        }
    }
}

// ------------- MFMA flash attention: 4-wave k-split, 2 q-tiles/block ------------
// R20 config (measured best: 114.55 us; untouched — isolate the qkv variable).
__global__ __launch_bounds__(256) void attn_kernel(
    const unsigned short* __restrict__ qF, const unsigned short* __restrict__ kF,
    const unsigned short* __restrict__ vF, const float* __restrict__ mask,
    float* __restrict__ out)
{
    __shared__ __align__(16) unsigned short pS[4][16][88];  // wave-private P tiles
    __shared__ float oS[3][64][17];          // o[16] + l in slot 16; stride 17 odd

    const int tid  = threadIdx.x;
    const int w    = tid >> 6;
    const int lane = tid & 63;
    const int q16  = lane & 15;
    const int quad = lane >> 4;
    const int bid  = blockIdx.x;
    const int b    = bid & 7;                    // batches interleaved (XCD affinity)
    const int g    = 63 - (bid >> 3);            // heavy q-pairs first (LPT)
    const int qtA  = 2 * g, qtB = 2 * g + 1;
    const int qrowA = (qtA << 4) + q16;
    const int qrowB = qrowA + 16;

    const size_t qbaseA = ((size_t)(b * 128 + qtA) * 2) * 512 + lane * 8;
    const size_t qbaseB = ((size_t)(b * 128 + qtB) * 2) * 512 + lane * 8;
    bf16x8 qfA0 = *(const bf16x8*)(qF + qbaseA);
    bf16x8 qfA1 = *(const bf16x8*)(qF + qbaseA + 512);
    bf16x8 qfB0 = *(const bf16x8*)(qF + qbaseB);
    bf16x8 qfB1 = *(const bf16x8*)(qF + qbaseB + 512);
    // fold 1/sqrt(64) and log2(e): softmax runs in base-2 domain
    const float mrowA  = mask[b * T_ + qrowA];
    const float mrowB  = mask[b * T_ + qrowB];
    const float maskvA = mrowA * 0.125f * 1.44269504f;
    const float maskvB = mrowB * 0.125f * 1.44269504f;

    f32x4 oA[4] = {}, oB[4] = {};
    float lA = 0.f, lB = 0.f;

    const int niter = ((qtB << 4) + 16 + 63) >> 6;  // same for qtA
    const int dt    = niter - 1;                    // diagonal tile index

    bf16x8 kf[8], vf[8];
    auto loadK = [&](int kt_) {
        #pragma unroll
        for (int sub = 0; sub < 4; sub++) {
            const unsigned short* kp = kF + ((size_t)(b * 128 + kt_ * 4 + sub) * 2) * 512 + lane * 8;
            kf[2 * sub]     = *(const bf16x8*)(kp);
            kf[2 * sub + 1] = *(const bf16x8*)(kp + 512);
        }
    };
    auto loadV = [&](int kt_) {
        #pragma unroll
        for (int ht = 0; ht < 4; ht++) {
            const unsigned short* vp = vF + ((size_t)(b * 64 + kt_ * 2) * 4 + ht) * 512 + lane * 8;
            vf[2 * ht]     = *(const bf16x8*)(vp);
            vf[2 * ht + 1] = *(const bf16x8*)(vp + 4 * 512);
        }
    };

    if (w < niter) { loadK(w); loadV(w); }       // prologue (wave-uniform guard)

    for (int kt = w; kt < niter; kt += 4) {
        const int kbase = kt << 6;
        const bool more = (kt + 4 < niter);      // wave-uniform

        // ---- S^T = K.Q^T for BOTH tiles (kf dies after saB)
        f32x4 saA[4] = {}, saB[4] = {};
        #pragma unroll
        for (int sub = 0; sub < 4; sub++) {
            saA[sub] = __builtin_amdgcn_mfma_f32_16x16x32_bf16(kf[2 * sub],     qfA0, saA[sub], 0, 0, 0);
            saA[sub] = __builtin_amdgcn_mfma_f32_16x16x32_bf16(kf[2 * sub + 1], qfA1, saA[sub], 0, 0, 0);
            saB[sub] = __builtin_amdgcn_mfma_f32_16x16x32_bf16(kf[2 * sub],     qfB0, saB[sub], 0, 0, 0);
            saB[sub] = __builtin_amdgcn_mfma_f32_16x16x32_bf16(kf[2 * sub + 1], qfB1, saB[sub], 0, 0, 0);
        }
        if (more) loadK(kt + 4);                 // prefetch next K into dead kf

        // ---- tile A: softmax + PV  (pS[w] used then released)
        {
            float p[16];
            if (kt != dt) {
                #pragma unroll
                for (int e = 0; e < 16; e++)
                    p[e] = __builtin_amdgcn_exp2f(saA[e >> 2][e & 3] * maskvA);
            } else {
                #pragma unroll
                for (int sub = 0; sub < 4; sub++)
                    #pragma unroll
                    for (int r = 0; r < 4; r++) {
                        int kidx = kbase + sub * 16 + quad * 4 + r;
                        float sv = saA[sub][r] * maskvA;
                        sv = (kidx > qrowA) ? -__builtin_inff() : sv;
                        p[sub * 4 + r] = __builtin_amdgcn_exp2f(sv);
                    }
            }
            lA += (((p[0] + p[1]) + (p[2] + p[3])) + ((p[4] + p[5]) + (p[6] + p[7])))
                + (((p[8] + p[9]) + (p[10] + p[11])) + ((p[12] + p[13]) + (p[14] + p[15])));
            #pragma unroll
            for (int sub = 0; sub < 4; sub++) {
                unsigned int lo = (unsigned int)f2bf(p[sub * 4 + 0]) | ((unsigned int)f2bf(p[sub * 4 + 1]) << 16);
                unsigned int hi = (unsigned int)f2bf(p[sub * 4 + 2]) | ((unsigned int)f2bf(p[sub * 4 + 3]) << 16);
                *(uint2*)&pS[w][q16][sub * 16 + quad * 4] = make_uint2(lo, hi);
            }
            bf16x8 pf0 = *(const bf16x8*)&pS[w][q16][quad * 8];
            bf16x8 pf1 = *(const bf16x8*)&pS[w][q16][32 + quad * 8];
            #pragma unroll
            for (int ht = 0; ht < 4; ht++) {
                oA[ht] = __builtin_amdgcn_mfma_f32_16x16x32_bf16(vf[2 * ht],     pf0, oA[ht], 0, 0, 0);
                oA[ht] = __builtin_amdgcn_mfma_f32_16x16x32_bf16(vf[2 * ht + 1], pf1, oA[ht], 0, 0, 0);
            }
        }

        // ---- tile B: softmax + PV  (pS[w] reused; intra-wave WAR ordering)
        {
            float p[16];
            if (kt != dt) {
                #pragma unroll
                for (int e = 0; e < 16; e++)
                    p[e] = __builtin_amdgcn_exp2f(saB[e >> 2][e & 3] * maskvB);
            } else {
                #pragma unroll
                for (int sub = 0; sub < 4; sub++)
                    #pragma unroll
                    for (int r = 0; r < 4; r++) {
                        int kidx = kbase + sub * 16 + quad * 4 + r;
                        float sv = saB[sub][r] * maskvB;
                        sv = (kidx > qrowB) ? -__builtin_inff() : sv;
                        p[sub * 4 + r] = __builtin_amdgcn_exp2f(sv);
                    }
            }
            lB += (((p[0] + p[1]) + (p[2] + p[3])) + ((p[4] + p[5]) + (p[6] + p[7])))
                + (((p[8] + p[9]) + (p[10] + p[11])) + ((p[12] + p[13]) + (p[14] + p[15])));
            #pragma unroll
            for (int sub = 0; sub < 4; sub++) {
                unsigned int lo = (unsigned int)f2bf(p[sub * 4 + 0]) | ((unsigned int)f2bf(p[sub * 4 + 1]) << 16);
                unsigned int hi = (unsigned int)f2bf(p[sub * 4 + 2]) | ((unsigned int)f2bf(p[sub * 4 + 3]) << 16);
                *(uint2*)&pS[w][q16][sub * 16 + quad * 4] = make_uint2(lo, hi);
            }
            bf16x8 pf0 = *(const bf16x8*)&pS[w][q16][quad * 8];
            bf16x8 pf1 = *(const bf16x8*)&pS[w][q16][32 + quad * 8];
            #pragma unroll
            for (int ht = 0; ht < 4; ht++) {
                oB[ht] = __builtin_amdgcn_mfma_f32_16x16x32_bf16(vf[2 * ht],     pf0, oB[ht], 0, 0, 0);
                oB[ht] = __builtin_amdgcn_mfma_f32_16x16x32_bf16(vf[2 * ht + 1], pf1, oB[ht], 0, 0, 0);
            }
        }
        if (more) loadV(kt + 4);                 // prefetch next V into dead vf
    }

    // deferred cross-lane l reduction (k spans the quad dimension)
    lA += __shfl_xor(lA, 16); lA += __shfl_xor(lA, 32);
    lB += __shfl_xor(lB, 16); lB += __shfl_xor(lB, 32);

    // ---- merge tile A (oS reused for B afterwards)
    if (w > 0) {
        #pragma unroll
        for (int ht = 0; ht < 4; ht++)
            #pragma unroll
            for (int r = 0; r < 4; r++) oS[w - 1][lane][ht * 4 + r] = oA[ht][r];
        oS[w - 1][lane][16] = lA;
    }
    __syncthreads();
    if (w == 0) {
        #pragma unroll
        for (int j = 0; j < 3; j++) {
            #pragma unroll
            for (int ht = 0; ht < 4; ht++)
                #pragma unroll
                for (int r = 0; r < 4; r++) oA[ht][r] += oS[j][lane][ht * 4 + r];
            lA += oS[j][lane][16];
        }
        const float invl = (mrowA != 0.f && lA > 0.f) ? (1.f / lA) : 0.f;
        #pragma unroll
        for (int ht = 0; ht < 4; ht++) {
            float4 ov = make_float4(oA[ht][0] * invl, oA[ht][1] * invl,
                                    oA[ht][2] * invl, oA[ht][3] * invl);
            *(float4*)(out + ((size_t)(b * T_) + qrowA) * H_ + ht * 16 + quad * 4) = ov;
        }
    }
    __syncthreads();                             // w0 done reading oS(A)

    // ---- merge tile B
    if (w > 0) {
        #pragma unroll
        for (int ht = 0; ht < 4; ht++)
            #pragma unroll
            for (int r = 0; r < 4; r++) oS[w - 1][lane][ht * 4 + r] = oB[ht][r];
        oS[w - 1][lane][16] = lB;
    }
    __syncthreads();
    if (w == 0) {
        #pragma unroll
        for (int j = 0; j < 3; j++) {
            #pragma unroll
            for (int ht = 0; ht < 4; ht++)
                #pragma unroll
                for (int r = 0; r < 4; r++) oB[ht][r] += oS[j][lane][ht * 4 + r];
            lB += oS[j][lane][16];
        }
        const float invl = (mrowB != 0.f && lB > 0.f) ? (1.f / lB) : 0.f;
        #pragma unroll
        for (int ht = 0; ht < 4; ht++) {
            float4 ov = make_float4(oB[ht][0] * invl, oB[ht][1] * invl,
                                    oB[ht][2] * invl, oB[ht][3] * invl);
            *(float4*)(out + ((size_t)(b * T_) + qrowB) * H_ + ht * 16 + quad * 4) = ov;
        }
    }
}

extern "C" void kernel_launch(void* const* d_in, const int* in_sizes, int n_in,
                              void* d_out, int out_size, void* d_ws, size_t ws_size,
                              hipStream_t stream) {
    const float* x    = (const float*)d_in[0];
    const float* mask = (const float*)d_in[1];
    const float* Wq   = (const float*)d_in[2];
    const float* Wk   = (const float*)d_in[3];
    const float* Wv   = (const float*)d_in[4];
    float* out = (float*)d_out;

    unsigned short* qf = (unsigned short*)d_ws;            // bf16 frag-packed [BT*H]
    unsigned short* kf = qf + (size_t)BT_ * H_;
    unsigned short* vf = kf + (size_t)BT_ * H_;
    unsigned short* wt = vf + (size_t)BT_ * H_;            // bf16 WTf[24][12][64][8]

    wprep<<<72, 256, 0, stream>>>(Wq, Wk, Wv, wt);
    qkv_kernel<<<BT_ / 16, 256, 0, stream>>>(x, wt, qf, kf, vf);
    attn_kernel<<<B_ * (T_ / 32), 256, 0, stream>>>(qf, kf, vf, mask, out);
}